// Round 1
// baseline (211.036 us; speedup 1.0000x reference)
//
#include <hip/hip_runtime.h>

// Problem constants (from reference): B=16, L=4096, D=512, HORIZON=100
constexpr int Bc = 16;
constexpr int Lc = 4096;
constexpr int Dc = 512;
constexpr int D4 = Dc / 4;               // 128 float4 per row
constexpr int ROWS = Bc * (Lc + 1);      // 65552
constexpr int TOTAL4 = ROWS * D4;        // 8,390,656

__global__ __launch_bounds__(256) void pe_kernel(
    const float* __restrict__ tokens,
    const int*   __restrict__ lengths,
    const float* __restrict__ cls,
    float*       __restrict__ out)
{
    int t = blockIdx.x * 256 + threadIdx.x;      // float4 index into out
    if (t >= TOTAL4) return;

    int d4  = t & (D4 - 1);                      // which float4 within row
    int row = t >> 7;                            // t / 128
    int b   = row / (Lc + 1);
    int l   = row - b * (Lc + 1);
    int len = lengths[b];
    int d0  = d4 << 2;                           // element index (multiple of 4)

    float4 r;
    if (l < len) {
        // valid token row (l < len <= L, so l indexes tokens)
        const float4 tok = *reinterpret_cast<const float4*>(
            tokens + ((size_t)(b * Lc + l) << 9) + d0);

        // coef(d) = 100^{-(d - d%2)/512} + (pi/2)*(d%2); work in revolutions.
        // freq_rev = exp2(-(d&~1) * log2(100)/512) / (2*pi); phase_rev = 0.25*(d&1)
        const float K      = 6.6438561897747395f / 512.0f;  // log2(100)/512
        const float INV2PI = 0.15915493667125702f;          // 1/(2*pi)

        float f0 = __builtin_exp2f(-(float)d0       * K) * INV2PI;  // d0, d0+1 (even pair)
        float f2 = __builtin_exp2f(-(float)(d0 + 2) * K) * INV2PI;  // d0+2, d0+3
        float c0 = f0;
        float c1 = f0 + 0.25f;   // + (pi/2)/(2*pi)
        float c2 = f2;
        float c3 = f2 + 0.25f;

        float lf = (float)l;
        float r0 = __builtin_amdgcn_fractf(lf * c0);
        float r1 = __builtin_amdgcn_fractf(lf * c1);
        float r2 = __builtin_amdgcn_fractf(lf * c2);
        float r3 = __builtin_amdgcn_fractf(lf * c3);

        r.x = tok.x + __builtin_amdgcn_sinf(r0);
        r.y = tok.y + __builtin_amdgcn_sinf(r1);
        r.z = tok.z + __builtin_amdgcn_sinf(r2);
        r.w = tok.w + __builtin_amdgcn_sinf(r3);
    } else if (l == len) {
        // CLS row: masked-out token row (or the extra L-th row) gets exactly cls
        r = *reinterpret_cast<const float4*>(cls + d0);
    } else {
        r = make_float4(0.f, 0.f, 0.f, 0.f);
    }

    reinterpret_cast<float4*>(out)[t] = r;
}

extern "C" void kernel_launch(void* const* d_in, const int* in_sizes, int n_in,
                              void* d_out, int out_size, void* d_ws, size_t ws_size,
                              hipStream_t stream) {
    const float* tokens  = (const float*)d_in[0];
    const int*   lengths = (const int*)d_in[1];
    const float* cls     = (const float*)d_in[2];
    float*       out     = (float*)d_out;

    int blocks = (TOTAL4 + 255) / 256;   // 32776
    pe_kernel<<<blocks, 256, 0, stream>>>(tokens, lengths, cls, out);
}